// Round 5
// baseline (98.537 us; speedup 1.0000x reference)
//
#include <hip/hip_runtime.h>
#include <hip/hip_fp16.h>
#include <stdint.h>

// Problem constants: Xp(16384,3) X(8192,3) W(64,8192) eps scalar -> out(16384,64)
#define M_ROWS 16384
#define N_PTS  8192
#define K_OUT  64

typedef _Float16       h2    __attribute__((ext_vector_type(2)));
typedef unsigned short u16x2 __attribute__((ext_vector_type(2)));
typedef _Float16       f16x8 __attribute__((ext_vector_type(8)));
typedef float          f32x4 __attribute__((ext_vector_type(4)));

union AF { f16x8 v; uint4 q; uint32_t u[4]; h2 h[4]; };

__device__ __forceinline__ h2 pkrtz2(float a, float b) {
    return __builtin_bit_cast(h2, __builtin_amdgcn_cvt_pkrtz(a, b));
}
__device__ __forceinline__ uint32_t pkrtz(float a, float b) {
    return __builtin_bit_cast(uint32_t, __builtin_amdgcn_cvt_pkrtz(a, b));
}

// packed fast sqrt(t), t in [1, ~512]: per-half rsqrt bit-seed (0x59BA - (u>>1),
// packed 16-bit ops so no cross-half contamination) + 1 reassociated Newton:
// y = t*r0; p = y*r0; k = 1.5 - 0.5*p; phi = y*k.  6 packed VALU ops / 2 phis.
// Rel err <= ~3e-3 (validated: absmax 8 vs threshold 21.28).
__device__ __forceinline__ h2 pk_sqrt_fast(h2 t, h2 mhf, h2 c15) {
    u16x2 u = __builtin_bit_cast(u16x2, t);
    u16x2 r0u = (u16x2){0x59BA, 0x59BA} - (u >> 1);
    h2 r0 = __builtin_bit_cast(h2, r0u);
    h2 y = t * r0;
    h2 p = y * r0;
    h2 k = __builtin_elementwise_fma(p, mhf, c15);
    return y * k;
}

// ---------------- prep ----------------
// blocks [0,256):   W -> fragment-linear f16 Wt (B-frag order for 16x16x32):
//                   Wt uint4 idx (b*4+kt)*64+lane = W[kt*16+(lane&15)][b*32+(lane>>4)*8+j]
// blocks [256,272): coord streams as packed-f16 pairs (4096 dwords each):
//                   Cx = -2*eps*x, Cy, Cz, Cc = |eps*x|^2 + 1
__global__ __launch_bounds__(256) void rbf_prep(
    const float* __restrict__ Wf, const float* __restrict__ X,
    const float* __restrict__ epsp,
    uint4* __restrict__ Wt, uint32_t* __restrict__ Cx,
    uint32_t* __restrict__ Cy, uint32_t* __restrict__ Cz,
    uint32_t* __restrict__ Cc)
{
    const int bid = blockIdx.x, tid = threadIdx.x;
    if (bid < 256) {
        const int kt = tid >> 6, lane = tid & 63;
        const int l15 = lane & 15, g = lane >> 4;
        const int row = kt * 16 + l15;
        const int col = bid * 32 + g * 8;
        const float4* src = (const float4*)(Wf + row * N_PTS + col);
        const float4 w0 = src[0], w1 = src[1];
        uint4 p;
        p.x = pkrtz(w0.x, w0.y);
        p.y = pkrtz(w0.z, w0.w);
        p.z = pkrtz(w1.x, w1.y);
        p.w = pkrtz(w1.z, w1.w);
        Wt[(bid * 4 + kt) * 64 + lane] = p;
    } else {
        const int n = (bid - 256) * 256 + tid;       // pair index [0, 4096)
        const float e = *epsp;
        const float2 A = *(const float2*)(X + 6 * n);      // x0 y0
        const float2 B = *(const float2*)(X + 6 * n + 2);  // z0 x1
        const float2 C = *(const float2*)(X + 6 * n + 4);  // y1 z1
        const float x0 = A.x * e, y0 = A.y * e, z0 = B.x * e;
        const float x1 = B.y * e, y1 = C.x * e, z1 = C.y * e;
        Cx[n] = pkrtz(-2.0f * x0, -2.0f * x1);
        Cy[n] = pkrtz(-2.0f * y0, -2.0f * y1);
        Cz[n] = pkrtz(-2.0f * z0, -2.0f * z1);
        Cc[n] = pkrtz(fmaf(x0, x0, fmaf(y0, y0, fmaf(z0, z0, 1.0f))),
                      fmaf(x1, x1, fmaf(y1, y1, fmaf(z1, z1, 1.0f))));
    }
}

// one pipeline stage: build phi fragments from coord vectors + 8 MFMA (t=2)
__device__ __forceinline__ void rbf_step(
    const uint4& vx, const uint4& vy, const uint4& vz, const uint4& vc,
    const AF& wf0, const AF& wf1, const AF& wf2, const AF& wf3,
    const h2* pxk, const h2* pyk, const h2* pzk, const h2* aak,
    h2 mhf, h2 c15, f32x4 acc[2][4])
{
    const h2 cx[4] = {__builtin_bit_cast(h2, vx.x), __builtin_bit_cast(h2, vx.y),
                      __builtin_bit_cast(h2, vx.z), __builtin_bit_cast(h2, vx.w)};
    const h2 cy[4] = {__builtin_bit_cast(h2, vy.x), __builtin_bit_cast(h2, vy.y),
                      __builtin_bit_cast(h2, vy.z), __builtin_bit_cast(h2, vy.w)};
    const h2 cz[4] = {__builtin_bit_cast(h2, vz.x), __builtin_bit_cast(h2, vz.y),
                      __builtin_bit_cast(h2, vz.z), __builtin_bit_cast(h2, vz.w)};
    const h2 cc[4] = {__builtin_bit_cast(h2, vc.x), __builtin_bit_cast(h2, vc.y),
                      __builtin_bit_cast(h2, vc.z), __builtin_bit_cast(h2, vc.w)};

    #pragma unroll
    for (int t = 0; t < 2; ++t) {
        AF af;
        #pragma unroll
        for (int j = 0; j < 4; ++j) {
            h2 d = cc[j] + aak[t];
            d = __builtin_elementwise_fma(pxk[t], cx[j], d);
            d = __builtin_elementwise_fma(pyk[t], cy[j], d);
            d = __builtin_elementwise_fma(pzk[t], cz[j], d);
            af.h[j] = pk_sqrt_fast(d, mhf, c15);
        }
        acc[t][0] = __builtin_amdgcn_mfma_f32_16x16x32_f16(af.v, wf0.v, acc[t][0], 0, 0, 0);
        acc[t][1] = __builtin_amdgcn_mfma_f32_16x16x32_f16(af.v, wf1.v, acc[t][1], 0, 0, 0);
        acc[t][2] = __builtin_amdgcn_mfma_f32_16x16x32_f16(af.v, wf2.v, acc[t][2], 0, 0, 0);
        acc[t][3] = __builtin_amdgcn_mfma_f32_16x16x32_f16(af.v, wf3.v, acc[t][3], 0, 0, 0);
    }
}

// ---------------- main: split-N in-block, LDS cross-wave reduce, no atomics --------
// Base = r2's 42 us kernel (t=2, 512x512, 1-deep prefetch, 32 KB LDS, (512,4)).
// NEW (r5): per-block ITERATION ROTATION to de-lockstep L2 access.
// Evidence (r0/r2/r4): time ~ 1/waves, traffic irrelevant, prefetch-1 null,
// effective load latency ~2000 cyc >> 200-cyc L2 hit. Cause: Wt/C addresses are
// blockIdx-INDEPENDENT -> all 512 blocks request the same cache line at the same
// loop step; the owning L2 bank serializes ~512 requests -> latency inflation at
// near-zero measured bandwidth. The s-loop is a commutative sum, so each block
// starts at rot=(bid>>3)&31 (same-XCD blocks get distinct rotations) and walks
// su=(s+rot)&31: concurrent readers per line drop ~512 -> ~16.
__global__ __launch_bounds__(512, 4) void rbf_main(
    const float* __restrict__ Xp, const uint4* __restrict__ Wt,
    const uint32_t* __restrict__ Cx, const uint32_t* __restrict__ Cy,
    const uint32_t* __restrict__ Cz, const uint32_t* __restrict__ Cc,
    const float* __restrict__ epsp, float* __restrict__ out)
{
    __shared__ __align__(16) float sR[4 * 32 * 64];   // 32 KB: [seg(4)][row(32)][col(64)]

    const int tid  = threadIdx.x;
    const int lane = tid & 63;
    const int wv   = tid >> 6;        // 0..7 = n-chunk
    const int m    = lane & 15;
    const int g    = lane >> 4;

    const int rowbase = blockIdx.x * 32;
    const int rot = (blockIdx.x >> 3) & 31;   // same-XCD neighbors -> distinct rot

    // per-lane row geometry for 2 tiles (rows rowbase + t*16 + m), f16 splat pairs
    const float e = *epsp;
    h2 pxk[2], pyk[2], pzk[2], aak[2];
    #pragma unroll
    for (int t = 0; t < 2; ++t) {
        const int r = rowbase + t * 16 + m;
        const float px = Xp[3 * r + 0] * e;
        const float py = Xp[3 * r + 1] * e;
        const float pz = Xp[3 * r + 2] * e;
        const float a  = fmaf(px, px, fmaf(py, py, pz * pz));
        pxk[t] = pkrtz2(px, px);
        pyk[t] = pkrtz2(py, py);
        pzk[t] = pkrtz2(pz, pz);
        aak[t] = pkrtz2(a, a);
    }
    const h2 mhf = {(_Float16)-0.5f, (_Float16)-0.5f};
    const h2 c15 = {(_Float16)1.5f, (_Float16)1.5f};

    f32x4 acc[2][4];
    #pragma unroll
    for (int t = 0; t < 2; ++t)
        #pragma unroll
        for (int kt = 0; kt < 4; ++kt)
            acc[t][kt] = (f32x4){0.f, 0.f, 0.f, 0.f};

    // uniform bases (wv, block only) — divergent part is a FIXED lane offset
    const uint32_t* cxp = Cx + wv * 512 + g * 4;   // + su*16 (SGPR-uniform)
    const uint32_t* cyp = Cy + wv * 512 + g * 4;
    const uint32_t* czp = Cz + wv * 512 + g * 4;
    const uint32_t* ccp = Cc + wv * 512 + g * 4;
    const uint4*    wp  = Wt + wv * 8192 + lane;   // + su*256 (SGPR) + kt*64 (imm)

    // ---- software pipeline: prologue loads for logical s=0 (su=rot) ----
    uint4 vx = *(const uint4*)(cxp + rot * 16);
    uint4 vy = *(const uint4*)(cyp + rot * 16);
    uint4 vz = *(const uint4*)(czp + rot * 16);
    uint4 vc = *(const uint4*)(ccp + rot * 16);
    AF wf0, wf1, wf2, wf3;
    wf0.q = wp[rot * 256];
    wf1.q = wp[rot * 256 + 64];
    wf2.q = wp[rot * 256 + 128];
    wf3.q = wp[rot * 256 + 192];

    #pragma unroll 4
    for (int s = 0; s < 31; ++s) {
        // issue logical iteration s+1's loads (rotated index) before computing s
        const int su = (s + 1 + rot) & 31;
        const uint4 nvx = *(const uint4*)(cxp + su * 16);
        const uint4 nvy = *(const uint4*)(cyp + su * 16);
        const uint4 nvz = *(const uint4*)(czp + su * 16);
        const uint4 nvc = *(const uint4*)(ccp + su * 16);
        AF nw0, nw1, nw2, nw3;
        nw0.q = wp[su * 256];
        nw1.q = wp[su * 256 + 64];
        nw2.q = wp[su * 256 + 128];
        nw3.q = wp[su * 256 + 192];

        rbf_step(vx, vy, vz, vc, wf0, wf1, wf2, wf3,
                 pxk, pyk, pzk, aak, mhf, c15, acc);

        vx = nvx; vy = nvy; vz = nvz; vc = nvc;
        wf0 = nw0; wf1 = nw1; wf2 = nw2; wf3 = nw3;
    }
    // epilogue: compute the last prefetched iteration
    rbf_step(vx, vy, vz, vc, wf0, wf1, wf2, wf3,
             pxk, pyk, pzk, aak, mhf, c15, acc);

    // ---- cross-wave reduction through LDS, two-phase (32 KB; verified r1/r2) ----
    // D layout: acc[t][kt][reg] = partial out[rowbase + t*16 + g*4 + reg][kt*16 + m]
    {
        float* base = sR + (wv & 3) * 2048;
        if (wv < 4) {
            #pragma unroll
            for (int t = 0; t < 2; ++t)
                #pragma unroll
                for (int kt = 0; kt < 4; ++kt)
                    #pragma unroll
                    for (int reg = 0; reg < 4; ++reg)
                        base[(t * 16 + g * 4 + reg) * 64 + kt * 16 + m] = acc[t][kt][reg];
        }
        __syncthreads();
        if (wv >= 4) {
            #pragma unroll
            for (int t = 0; t < 2; ++t)
                #pragma unroll
                for (int kt = 0; kt < 4; ++kt)
                    #pragma unroll
                    for (int reg = 0; reg < 4; ++reg)
                        base[(t * 16 + g * 4 + reg) * 64 + kt * 16 + m] += acc[t][kt][reg];
        }
        __syncthreads();
    }

    // 512 threads: thread -> (row = tid>>4, kq = tid&15), sum 4 segments, store
    {
        const int row = tid >> 4;
        const int kq  = tid & 15;
        const float* p = sR + row * 64 + kq * 4;
        float4 s0 = *(const float4*)(p);
        #pragma unroll
        for (int w = 1; w < 4; ++w) {
            const float4 sw = *(const float4*)(p + w * 2048);
            s0.x += sw.x; s0.y += sw.y; s0.z += sw.z; s0.w += sw.w;
        }
        *(float4*)(out + (rowbase + row) * K_OUT + kq * 4) = s0;
    }
}

extern "C" void kernel_launch(void* const* d_in, const int* in_sizes, int n_in,
                              void* d_out, int out_size, void* d_ws, size_t ws_size,
                              hipStream_t stream) {
    (void)in_sizes; (void)n_in; (void)out_size; (void)ws_size;
    const float* Xp  = (const float*)d_in[0];   // (16384,3)
    const float* X   = (const float*)d_in[1];   // (8192,3)
    const float* Wf  = (const float*)d_in[2];   // (64,8192)
    const float* eps = (const float*)d_in[3];   // scalar
    float* out = (float*)d_out;                 // (16384,64)

    // ws: Wt (fragment-linear f16 W) 1 MiB | Cx,Cy,Cz,Cc 16 KiB each
    uint4*    Wt = (uint4*)d_ws;
    uint32_t* Cx = (uint32_t*)((char*)d_ws + (1u << 20));
    uint32_t* Cy = Cx + 4096;
    uint32_t* Cz = Cy + 4096;
    uint32_t* Cc = Cz + 4096;

    rbf_prep<<<dim3(272), dim3(256), 0, stream>>>(Wf, X, eps, Wt, Cx, Cy, Cz, Cc);
    rbf_main<<<dim3(M_ROWS / 32), dim3(512), 0, stream>>>(
        Xp, Wt, Cx, Cy, Cz, Cc, eps, out);
}

// Round 6
// 97.863 us; speedup vs baseline: 1.0069x; 1.0069x over previous
//
#include <hip/hip_runtime.h>
#include <hip/hip_fp16.h>
#include <stdint.h>

// Problem constants: Xp(16384,3) X(8192,3) W(64,8192) eps scalar -> out(16384,64)
#define M_ROWS 16384
#define N_PTS  8192
#define K_OUT  64

typedef _Float16       h2    __attribute__((ext_vector_type(2)));
typedef unsigned short u16x2 __attribute__((ext_vector_type(2)));
typedef _Float16       f16x8 __attribute__((ext_vector_type(8)));
typedef float          f32x4 __attribute__((ext_vector_type(4)));

union AF { f16x8 v; uint4 q; uint32_t u[4]; h2 h[4]; };

__device__ __forceinline__ h2 pkrtz2(float a, float b) {
    return __builtin_bit_cast(h2, __builtin_amdgcn_cvt_pkrtz(a, b));
}
__device__ __forceinline__ uint32_t pkrtz(float a, float b) {
    return __builtin_bit_cast(uint32_t, __builtin_amdgcn_cvt_pkrtz(a, b));
}

// packed fast sqrt(t), t in [1, ~512]: per-half rsqrt bit-seed (0x59BA - (u>>1),
// packed 16-bit ops so no cross-half contamination) + 1 reassociated Newton:
// y = t*r0; p = y*r0; k = 1.5 - 0.5*p; phi = y*k.  6 packed VALU ops / 2 phis.
// Rel err <= ~3e-3 (validated: absmax 8 vs threshold 21.28).
__device__ __forceinline__ h2 pk_sqrt_fast(h2 t, h2 mhf, h2 c15) {
    u16x2 u = __builtin_bit_cast(u16x2, t);
    u16x2 r0u = (u16x2){0x59BA, 0x59BA} - (u >> 1);
    h2 r0 = __builtin_bit_cast(h2, r0u);
    h2 y = t * r0;
    h2 p = y * r0;
    h2 k = __builtin_elementwise_fma(p, mhf, c15);
    return y * k;
}

// ---------------- prep ----------------
// blocks [0,256):   W -> fragment-linear f16 Wt (B-frag order for 16x16x32):
//                   Wt uint4 idx (b*4+kt)*64+lane = W[kt*16+(lane&15)][b*32+(lane>>4)*8+j]
// blocks [256,272): coord streams as packed-f16 pairs (4096 dwords each):
//                   Cx = -2*eps*x, Cy, Cz, Cc = |eps*x|^2 + 1
__global__ __launch_bounds__(256) void rbf_prep(
    const float* __restrict__ Wf, const float* __restrict__ X,
    const float* __restrict__ epsp,
    uint4* __restrict__ Wt, uint32_t* __restrict__ Cx,
    uint32_t* __restrict__ Cy, uint32_t* __restrict__ Cz,
    uint32_t* __restrict__ Cc)
{
    const int bid = blockIdx.x, tid = threadIdx.x;
    if (bid < 256) {
        const int kt = tid >> 6, lane = tid & 63;
        const int l15 = lane & 15, g = lane >> 4;
        const int row = kt * 16 + l15;
        const int col = bid * 32 + g * 8;
        const float4* src = (const float4*)(Wf + row * N_PTS + col);
        const float4 w0 = src[0], w1 = src[1];
        uint4 p;
        p.x = pkrtz(w0.x, w0.y);
        p.y = pkrtz(w0.z, w0.w);
        p.z = pkrtz(w1.x, w1.y);
        p.w = pkrtz(w1.z, w1.w);
        Wt[(bid * 4 + kt) * 64 + lane] = p;
    } else {
        const int n = (bid - 256) * 256 + tid;       // pair index [0, 4096)
        const float e = *epsp;
        const float2 A = *(const float2*)(X + 6 * n);      // x0 y0
        const float2 B = *(const float2*)(X + 6 * n + 2);  // z0 x1
        const float2 C = *(const float2*)(X + 6 * n + 4);  // y1 z1
        const float x0 = A.x * e, y0 = A.y * e, z0 = B.x * e;
        const float x1 = B.y * e, y1 = C.x * e, z1 = C.y * e;
        Cx[n] = pkrtz(-2.0f * x0, -2.0f * x1);
        Cy[n] = pkrtz(-2.0f * y0, -2.0f * y1);
        Cz[n] = pkrtz(-2.0f * z0, -2.0f * z1);
        Cc[n] = pkrtz(fmaf(x0, x0, fmaf(y0, y0, fmaf(z0, z0, 1.0f))),
                      fmaf(x1, x1, fmaf(y1, y1, fmaf(z1, z1, 1.0f))));
    }
}

// one pipeline stage: build phi fragments from coord vectors + 8 MFMA (t=2)
__device__ __forceinline__ void rbf_step(
    const uint4& vx, const uint4& vy, const uint4& vz, const uint4& vc,
    const AF& wf0, const AF& wf1, const AF& wf2, const AF& wf3,
    const h2* pxk, const h2* pyk, const h2* pzk, const h2* aak,
    h2 mhf, h2 c15, f32x4 acc[2][4])
{
    const h2 cx[4] = {__builtin_bit_cast(h2, vx.x), __builtin_bit_cast(h2, vx.y),
                      __builtin_bit_cast(h2, vx.z), __builtin_bit_cast(h2, vx.w)};
    const h2 cy[4] = {__builtin_bit_cast(h2, vy.x), __builtin_bit_cast(h2, vy.y),
                      __builtin_bit_cast(h2, vy.z), __builtin_bit_cast(h2, vy.w)};
    const h2 cz[4] = {__builtin_bit_cast(h2, vz.x), __builtin_bit_cast(h2, vz.y),
                      __builtin_bit_cast(h2, vz.z), __builtin_bit_cast(h2, vz.w)};
    const h2 cc[4] = {__builtin_bit_cast(h2, vc.x), __builtin_bit_cast(h2, vc.y),
                      __builtin_bit_cast(h2, vc.z), __builtin_bit_cast(h2, vc.w)};

    #pragma unroll
    for (int t = 0; t < 2; ++t) {
        AF af;
        #pragma unroll
        for (int j = 0; j < 4; ++j) {
            h2 d = cc[j] + aak[t];
            d = __builtin_elementwise_fma(pxk[t], cx[j], d);
            d = __builtin_elementwise_fma(pyk[t], cy[j], d);
            d = __builtin_elementwise_fma(pzk[t], cz[j], d);
            af.h[j] = pk_sqrt_fast(d, mhf, c15);
        }
        acc[t][0] = __builtin_amdgcn_mfma_f32_16x16x32_f16(af.v, wf0.v, acc[t][0], 0, 0, 0);
        acc[t][1] = __builtin_amdgcn_mfma_f32_16x16x32_f16(af.v, wf1.v, acc[t][1], 0, 0, 0);
        acc[t][2] = __builtin_amdgcn_mfma_f32_16x16x32_f16(af.v, wf2.v, acc[t][2], 0, 0, 0);
        acc[t][3] = __builtin_amdgcn_mfma_f32_16x16x32_f16(af.v, wf3.v, acc[t][3], 0, 0, 0);
    }
}

// ---------------- main: split-N in-block, LDS cross-wave reduce, no atomics --------
// Base = r2 (t=2, 512x512, 32 KB LDS, (512,4)). NEW (r6): sched_barrier(0) pins the
// 1-deep prefetch. Evidence: r2/r5 VGPR_Count=52-64 proves the compiler SANK the
// prefetch loads to their uses (a real 1-deep pipeline needs ~85-100 arch VGPRs:
// 32 in-flight + 32 consumed + ~20 misc) -> the software pipeline never existed in
// the binary, every iteration eats the full load round-trip serially. This explains
// the whole record: time ~ issue/waves with ~9x inflation, all pipes <50%, rotation
// null, traffic irrelevant. sched_barrier(0) = "no instruction may cross" ->
// loads must issue before compute, live ranges forced. 116 regs total < 128 budget
// at (512,4): no spill (guardrail: FETCH/WRITE must stay ~4.7/4 MB).
__global__ __launch_bounds__(512, 4) void rbf_main(
    const float* __restrict__ Xp, const uint4* __restrict__ Wt,
    const uint32_t* __restrict__ Cx, const uint32_t* __restrict__ Cy,
    const uint32_t* __restrict__ Cz, const uint32_t* __restrict__ Cc,
    const float* __restrict__ epsp, float* __restrict__ out)
{
    __shared__ __align__(16) float sR[4 * 32 * 64];   // 32 KB: [seg(4)][row(32)][col(64)]

    const int tid  = threadIdx.x;
    const int lane = tid & 63;
    const int wv   = tid >> 6;        // 0..7 = n-chunk
    const int m    = lane & 15;
    const int g    = lane >> 4;

    const int rowbase = blockIdx.x * 32;

    // per-lane row geometry for 2 tiles (rows rowbase + t*16 + m), f16 splat pairs
    const float e = *epsp;
    h2 pxk[2], pyk[2], pzk[2], aak[2];
    #pragma unroll
    for (int t = 0; t < 2; ++t) {
        const int r = rowbase + t * 16 + m;
        const float px = Xp[3 * r + 0] * e;
        const float py = Xp[3 * r + 1] * e;
        const float pz = Xp[3 * r + 2] * e;
        const float a  = fmaf(px, px, fmaf(py, py, pz * pz));
        pxk[t] = pkrtz2(px, px);
        pyk[t] = pkrtz2(py, py);
        pzk[t] = pkrtz2(pz, pz);
        aak[t] = pkrtz2(a, a);
    }
    const h2 mhf = {(_Float16)-0.5f, (_Float16)-0.5f};
    const h2 c15 = {(_Float16)1.5f, (_Float16)1.5f};

    f32x4 acc[2][4];
    #pragma unroll
    for (int t = 0; t < 2; ++t)
        #pragma unroll
        for (int kt = 0; kt < 4; ++kt)
            acc[t][kt] = (f32x4){0.f, 0.f, 0.f, 0.f};

    // uniform bases (wv, block only) — divergent part is a FIXED lane offset
    const uint32_t* cxp = Cx + wv * 512 + g * 4;   // + s*16 (imm)
    const uint32_t* cyp = Cy + wv * 512 + g * 4;
    const uint32_t* czp = Cz + wv * 512 + g * 4;
    const uint32_t* ccp = Cc + wv * 512 + g * 4;
    const uint4*    wp  = Wt + wv * 8192 + lane;   // + s*256 (SGPR) + kt*64 (imm)

    // ---- software pipeline: prologue loads for s=0 ----
    uint4 vx = *(const uint4*)(cxp);
    uint4 vy = *(const uint4*)(cyp);
    uint4 vz = *(const uint4*)(czp);
    uint4 vc = *(const uint4*)(ccp);
    AF wf0, wf1, wf2, wf3;
    wf0.q = wp[0];
    wf1.q = wp[64];
    wf2.q = wp[128];
    wf3.q = wp[192];

    #pragma unroll 4
    for (int s = 0; s < 31; ++s) {
        // issue iteration s+1's loads...
        const uint4 nvx = *(const uint4*)(cxp + (s + 1) * 16);
        const uint4 nvy = *(const uint4*)(cyp + (s + 1) * 16);
        const uint4 nvz = *(const uint4*)(czp + (s + 1) * 16);
        const uint4 nvc = *(const uint4*)(ccp + (s + 1) * 16);
        AF nw0, nw1, nw2, nw3;
        nw0.q = wp[(s + 1) * 256];
        nw1.q = wp[(s + 1) * 256 + 64];
        nw2.q = wp[(s + 1) * 256 + 128];
        nw3.q = wp[(s + 1) * 256 + 192];

        // ...and PIN them: nothing may be scheduled across this point, so the 8
        // loads above cannot be sunk into/past the compute below. Their dest regs
        // stay live across rbf_step -> true 1-deep pipeline in the binary.
        __builtin_amdgcn_sched_barrier(0);

        rbf_step(vx, vy, vz, vc, wf0, wf1, wf2, wf3,
                 pxk, pyk, pzk, aak, mhf, c15, acc);

        vx = nvx; vy = nvy; vz = nvz; vc = nvc;
        wf0 = nw0; wf1 = nw1; wf2 = nw2; wf3 = nw3;
    }
    // epilogue: compute the last prefetched iteration
    rbf_step(vx, vy, vz, vc, wf0, wf1, wf2, wf3,
             pxk, pyk, pzk, aak, mhf, c15, acc);

    // ---- cross-wave reduction through LDS, two-phase (32 KB; verified r1/r2) ----
    // D layout: acc[t][kt][reg] = partial out[rowbase + t*16 + g*4 + reg][kt*16 + m]
    {
        float* base = sR + (wv & 3) * 2048;
        if (wv < 4) {
            #pragma unroll
            for (int t = 0; t < 2; ++t)
                #pragma unroll
                for (int kt = 0; kt < 4; ++kt)
                    #pragma unroll
                    for (int reg = 0; reg < 4; ++reg)
                        base[(t * 16 + g * 4 + reg) * 64 + kt * 16 + m] = acc[t][kt][reg];
        }
        __syncthreads();
        if (wv >= 4) {
            #pragma unroll
            for (int t = 0; t < 2; ++t)
                #pragma unroll
                for (int kt = 0; kt < 4; ++kt)
                    #pragma unroll
                    for (int reg = 0; reg < 4; ++reg)
                        base[(t * 16 + g * 4 + reg) * 64 + kt * 16 + m] += acc[t][kt][reg];
        }
        __syncthreads();
    }

    // 512 threads: thread -> (row = tid>>4, kq = tid&15), sum 4 segments, store
    {
        const int row = tid >> 4;
        const int kq  = tid & 15;
        const float* p = sR + row * 64 + kq * 4;
        float4 s0 = *(const float4*)(p);
        #pragma unroll
        for (int w = 1; w < 4; ++w) {
            const float4 sw = *(const float4*)(p + w * 2048);
            s0.x += sw.x; s0.y += sw.y; s0.z += sw.z; s0.w += sw.w;
        }
        *(float4*)(out + (rowbase + row) * K_OUT + kq * 4) = s0;
    }
}

extern "C" void kernel_launch(void* const* d_in, const int* in_sizes, int n_in,
                              void* d_out, int out_size, void* d_ws, size_t ws_size,
                              hipStream_t stream) {
    (void)in_sizes; (void)n_in; (void)out_size; (void)ws_size;
    const float* Xp  = (const float*)d_in[0];   // (16384,3)
    const float* X   = (const float*)d_in[1];   // (8192,3)
    const float* Wf  = (const float*)d_in[2];   // (64,8192)
    const float* eps = (const float*)d_in[3];   // scalar
    float* out = (float*)d_out;                 // (16384,64)

    // ws: Wt (fragment-linear f16 W) 1 MiB | Cx,Cy,Cz,Cc 16 KiB each
    uint4*    Wt = (uint4*)d_ws;
    uint32_t* Cx = (uint32_t*)((char*)d_ws + (1u << 20));
    uint32_t* Cy = Cx + 4096;
    uint32_t* Cz = Cy + 4096;
    uint32_t* Cc = Cz + 4096;

    rbf_prep<<<dim3(272), dim3(256), 0, stream>>>(Wf, X, eps, Wt, Cx, Cy, Cz, Cc);
    rbf_main<<<dim3(M_ROWS / 32), dim3(512), 0, stream>>>(
        Xp, Wt, Cx, Cy, Cz, Cc, eps, out);
}

// Round 8
// 96.143 us; speedup vs baseline: 1.0249x; 1.0179x over previous
//
#include <hip/hip_runtime.h>
#include <hip/hip_fp16.h>
#include <stdint.h>

// Problem constants: Xp(16384,3) X(8192,3) W(64,8192) eps scalar -> out(16384,64)
#define M_ROWS 16384
#define N_PTS  8192
#define K_OUT  64

typedef _Float16       h2    __attribute__((ext_vector_type(2)));
typedef _Float16       f16x8 __attribute__((ext_vector_type(8)));
typedef float          f32x4 __attribute__((ext_vector_type(4)));

union AF { f16x8 v; uint4 q; uint32_t u[4]; h2 h[4]; };

__device__ __forceinline__ h2 pkrtz2(float a, float b) {
    return __builtin_bit_cast(h2, __builtin_amdgcn_cvt_pkrtz(a, b));
}
__device__ __forceinline__ uint32_t pkrtz(float a, float b) {
    return __builtin_bit_cast(uint32_t, __builtin_amdgcn_cvt_pkrtz(a, b));
}

// r8: hardware f16 sqrt (TRANS pipe) replaces the 6-op packed Newton chain.
// Evidence: r2 vs r4 proved wall time tracks total VALU+MFMA issue work at a
// constant ~43-45% efficiency (halving traffic+waves with same total work = same
// time); so the lever is instruction COUNT. v_sqrt_f16 x2 (trans pipe, off the
// VALU issue path, no dependency chain) replaces 6 dependent packed-VALU ops.
// Also exact (accuracy improves vs 3e-3 approx).
__device__ __forceinline__ h2 pk_sqrt_hw(h2 t) {
    return __builtin_elementwise_sqrt(t);
}

// ---------------- prep ----------------
// blocks [0,256):   W -> fragment-linear f16 Wt (B-frag order for 16x16x32):
//                   Wt uint4 idx (b*4+kt)*64+lane = W[kt*16+(lane&15)][b*32+(lane>>4)*8+j]
// blocks [256,272): coord streams as packed-f16 pairs (4096 dwords each):
//                   Cx = -2*eps*x, Cy, Cz, Cc = |eps*x|^2 + 1
__global__ __launch_bounds__(256) void rbf_prep(
    const float* __restrict__ Wf, const float* __restrict__ X,
    const float* __restrict__ epsp,
    uint4* __restrict__ Wt, uint32_t* __restrict__ Cx,
    uint32_t* __restrict__ Cy, uint32_t* __restrict__ Cz,
    uint32_t* __restrict__ Cc)
{
    const int bid = blockIdx.x, tid = threadIdx.x;
    if (bid < 256) {
        const int kt = tid >> 6, lane = tid & 63;
        const int l15 = lane & 15, g = lane >> 4;
        const int row = kt * 16 + l15;
        const int col = bid * 32 + g * 8;
        const float4* src = (const float4*)(Wf + row * N_PTS + col);
        const float4 w0 = src[0], w1 = src[1];
        uint4 p;
        p.x = pkrtz(w0.x, w0.y);
        p.y = pkrtz(w0.z, w0.w);
        p.z = pkrtz(w1.x, w1.y);
        p.w = pkrtz(w1.z, w1.w);
        Wt[(bid * 4 + kt) * 64 + lane] = p;
    } else {
        const int n = (bid - 256) * 256 + tid;       // pair index [0, 4096)
        const float e = *epsp;
        const float2 A = *(const float2*)(X + 6 * n);      // x0 y0
        const float2 B = *(const float2*)(X + 6 * n + 2);  // z0 x1
        const float2 C = *(const float2*)(X + 6 * n + 4);  // y1 z1
        const float x0 = A.x * e, y0 = A.y * e, z0 = B.x * e;
        const float x1 = B.y * e, y1 = C.x * e, z1 = C.y * e;
        Cx[n] = pkrtz(-2.0f * x0, -2.0f * x1);
        Cy[n] = pkrtz(-2.0f * y0, -2.0f * y1);
        Cz[n] = pkrtz(-2.0f * z0, -2.0f * z1);
        Cc[n] = pkrtz(fmaf(x0, x0, fmaf(y0, y0, fmaf(z0, z0, 1.0f))),
                      fmaf(x1, x1, fmaf(y1, y1, fmaf(z1, z1, 1.0f))));
    }
}

// one pipeline stage: build phi fragments from coord vectors + 8 MFMA (t=2)
__device__ __forceinline__ void rbf_step(
    const uint4& vx, const uint4& vy, const uint4& vz, const uint4& vc,
    const AF& wf0, const AF& wf1, const AF& wf2, const AF& wf3,
    const h2* pxk, const h2* pyk, const h2* pzk, const h2* aak,
    f32x4 acc[2][4])
{
    const h2 cx[4] = {__builtin_bit_cast(h2, vx.x), __builtin_bit_cast(h2, vx.y),
                      __builtin_bit_cast(h2, vx.z), __builtin_bit_cast(h2, vx.w)};
    const h2 cy[4] = {__builtin_bit_cast(h2, vy.x), __builtin_bit_cast(h2, vy.y),
                      __builtin_bit_cast(h2, vy.z), __builtin_bit_cast(h2, vy.w)};
    const h2 cz[4] = {__builtin_bit_cast(h2, vz.x), __builtin_bit_cast(h2, vz.y),
                      __builtin_bit_cast(h2, vz.z), __builtin_bit_cast(h2, vz.w)};
    const h2 cc[4] = {__builtin_bit_cast(h2, vc.x), __builtin_bit_cast(h2, vc.y),
                      __builtin_bit_cast(h2, vc.z), __builtin_bit_cast(h2, vc.w)};

    #pragma unroll
    for (int t = 0; t < 2; ++t) {
        AF af;
        #pragma unroll
        for (int j = 0; j < 4; ++j) {
            h2 d = cc[j] + aak[t];
            d = __builtin_elementwise_fma(pxk[t], cx[j], d);
            d = __builtin_elementwise_fma(pyk[t], cy[j], d);
            d = __builtin_elementwise_fma(pzk[t], cz[j], d);
            af.h[j] = pk_sqrt_hw(d);
        }
        acc[t][0] = __builtin_amdgcn_mfma_f32_16x16x32_f16(af.v, wf0.v, acc[t][0], 0, 0, 0);
        acc[t][1] = __builtin_amdgcn_mfma_f32_16x16x32_f16(af.v, wf1.v, acc[t][1], 0, 0, 0);
        acc[t][2] = __builtin_amdgcn_mfma_f32_16x16x32_f16(af.v, wf2.v, acc[t][2], 0, 0, 0);
        acc[t][3] = __builtin_amdgcn_mfma_f32_16x16x32_f16(af.v, wf3.v, acc[t][3], 0, 0, 0);
    }
}

// ---------------- main: split-N in-block, LDS cross-wave reduce, no atomics --------
// Structure = r2's proven 42 us kernel (t=2, 512x512, 32 KB LDS, (512,4), 1-deep
// register prefetch). Only change vs r2: pk_sqrt_fast -> hardware v_sqrt_f16.
// (r7's manual vmcnt/LDS-DMA pipeline NaN'd on asm-constraint + LDS-aperture
// hazards and is abandoned; r2/r4 equivalence killed all memory-side theories.)
__global__ __launch_bounds__(512, 4) void rbf_main(
    const float* __restrict__ Xp, const uint4* __restrict__ Wt,
    const uint32_t* __restrict__ Cx, const uint32_t* __restrict__ Cy,
    const uint32_t* __restrict__ Cz, const uint32_t* __restrict__ Cc,
    const float* __restrict__ epsp, float* __restrict__ out)
{
    __shared__ __align__(16) float sR[4 * 32 * 64];   // 32 KB: [seg(4)][row(32)][col(64)]

    const int tid  = threadIdx.x;
    const int lane = tid & 63;
    const int wv   = tid >> 6;        // 0..7 = n-chunk
    const int m    = lane & 15;
    const int g    = lane >> 4;

    const int rowbase = blockIdx.x * 32;

    // per-lane row geometry for 2 tiles (rows rowbase + t*16 + m), f16 splat pairs
    const float e = *epsp;
    h2 pxk[2], pyk[2], pzk[2], aak[2];
    #pragma unroll
    for (int t = 0; t < 2; ++t) {
        const int r = rowbase + t * 16 + m;
        const float px = Xp[3 * r + 0] * e;
        const float py = Xp[3 * r + 1] * e;
        const float pz = Xp[3 * r + 2] * e;
        const float a  = fmaf(px, px, fmaf(py, py, pz * pz));
        pxk[t] = pkrtz2(px, px);
        pyk[t] = pkrtz2(py, py);
        pzk[t] = pkrtz2(pz, pz);
        aak[t] = pkrtz2(a, a);
    }

    f32x4 acc[2][4];
    #pragma unroll
    for (int t = 0; t < 2; ++t)
        #pragma unroll
        for (int kt = 0; kt < 4; ++kt)
            acc[t][kt] = (f32x4){0.f, 0.f, 0.f, 0.f};

    // uniform bases (wv, block only) — divergent part is a FIXED lane offset
    const uint32_t* cxp = Cx + wv * 512 + g * 4;   // + s*16 (imm)
    const uint32_t* cyp = Cy + wv * 512 + g * 4;
    const uint32_t* czp = Cz + wv * 512 + g * 4;
    const uint32_t* ccp = Cc + wv * 512 + g * 4;
    const uint4*    wp  = Wt + wv * 8192 + lane;   // + s*256 (SGPR) + kt*64 (imm)

    // ---- software pipeline: prologue loads for s=0 ----
    uint4 vx = *(const uint4*)(cxp);
    uint4 vy = *(const uint4*)(cyp);
    uint4 vz = *(const uint4*)(czp);
    uint4 vc = *(const uint4*)(ccp);
    AF wf0, wf1, wf2, wf3;
    wf0.q = wp[0];
    wf1.q = wp[64];
    wf2.q = wp[128];
    wf3.q = wp[192];

    #pragma unroll 4
    for (int s = 0; s < 31; ++s) {
        // issue iteration s+1's loads before computing iteration s
        const uint4 nvx = *(const uint4*)(cxp + (s + 1) * 16);
        const uint4 nvy = *(const uint4*)(cyp + (s + 1) * 16);
        const uint4 nvz = *(const uint4*)(czp + (s + 1) * 16);
        const uint4 nvc = *(const uint4*)(ccp + (s + 1) * 16);
        AF nw0, nw1, nw2, nw3;
        nw0.q = wp[(s + 1) * 256];
        nw1.q = wp[(s + 1) * 256 + 64];
        nw2.q = wp[(s + 1) * 256 + 128];
        nw3.q = wp[(s + 1) * 256 + 192];

        rbf_step(vx, vy, vz, vc, wf0, wf1, wf2, wf3,
                 pxk, pyk, pzk, aak, acc);

        vx = nvx; vy = nvy; vz = nvz; vc = nvc;
        wf0 = nw0; wf1 = nw1; wf2 = nw2; wf3 = nw3;
    }
    // epilogue: compute the last prefetched iteration
    rbf_step(vx, vy, vz, vc, wf0, wf1, wf2, wf3,
             pxk, pyk, pzk, aak, acc);

    // ---- cross-wave reduction through LDS, two-phase (32 KB; verified r1/r2) ----
    // D layout: acc[t][kt][reg] = partial out[rowbase + t*16 + g*4 + reg][kt*16 + m]
    {
        float* base = sR + (wv & 3) * 2048;
        if (wv < 4) {
            #pragma unroll
            for (int t = 0; t < 2; ++t)
                #pragma unroll
                for (int kt = 0; kt < 4; ++kt)
                    #pragma unroll
                    for (int reg = 0; reg < 4; ++reg)
                        base[(t * 16 + g * 4 + reg) * 64 + kt * 16 + m] = acc[t][kt][reg];
        }
        __syncthreads();
        if (wv >= 4) {
            #pragma unroll
            for (int t = 0; t < 2; ++t)
                #pragma unroll
                for (int kt = 0; kt < 4; ++kt)
                    #pragma unroll
                    for (int reg = 0; reg < 4; ++reg)
                        base[(t * 16 + g * 4 + reg) * 64 + kt * 16 + m] += acc[t][kt][reg];
        }
        __syncthreads();
    }

    // 512 threads: thread -> (row = tid>>4, kq = tid&15), sum 4 segments, store
    {
        const int row = tid >> 4;
        const int kq  = tid & 15;
        const float* p = sR + row * 64 + kq * 4;
        float4 s0 = *(const float4*)(p);
        #pragma unroll
        for (int w = 1; w < 4; ++w) {
            const float4 sw = *(const float4*)(p + w * 2048);
            s0.x += sw.x; s0.y += sw.y; s0.z += sw.z; s0.w += sw.w;
        }
        *(float4*)(out + (rowbase + row) * K_OUT + kq * 4) = s0;
    }
}

extern "C" void kernel_launch(void* const* d_in, const int* in_sizes, int n_in,
                              void* d_out, int out_size, void* d_ws, size_t ws_size,
                              hipStream_t stream) {
    (void)in_sizes; (void)n_in; (void)out_size; (void)ws_size;
    const float* Xp  = (const float*)d_in[0];   // (16384,3)
    const float* X   = (const float*)d_in[1];   // (8192,3)
    const float* Wf  = (const float*)d_in[2];   // (64,8192)
    const float* eps = (const float*)d_in[3];   // scalar
    float* out = (float*)d_out;                 // (16384,64)

    // ws: Wt (fragment-linear f16 W) 1 MiB | Cx,Cy,Cz,Cc 16 KiB each
    uint4*    Wt = (uint4*)d_ws;
    uint32_t* Cx = (uint32_t*)((char*)d_ws + (1u << 20));
    uint32_t* Cy = Cx + 4096;
    uint32_t* Cz = Cy + 4096;
    uint32_t* Cc = Cz + 4096;

    rbf_prep<<<dim3(272), dim3(256), 0, stream>>>(Wf, X, eps, Wt, Cx, Cy, Cz, Cc);
    rbf_main<<<dim3(M_ROWS / 32), dim3(512), 0, stream>>>(
        Xp, Wt, Cx, Cy, Cz, Cc, eps, out);
}